// Round 2
// baseline (2552.018 us; speedup 1.0000x reference)
//
#include <hip/hip_runtime.h>
#include <math.h>

#define CDIV(a,b) (((a)+(b)-1)/(b))

// ---------- edge prep: deg[dst] += 1 ----------
__global__ __launch_bounds__(256) void deg_kernel(
    const int* __restrict__ dst, int E, float* __restrict__ deg)
{
    int e = blockIdx.x * 256 + threadIdx.x;
    if (e >= E) return;
    atomicAdd(&deg[dst[e]], 1.0f);
}

__global__ __launch_bounds__(256) void dinv_kernel(float* __restrict__ deg, int N)
{
    int i = blockIdx.x * 256 + threadIdx.x;
    if (i >= N) return;
    deg[i] = 1.0f / sqrtf(deg[i] + 1.0f);  // +1 for self-loop
}

__global__ __launch_bounds__(256) void enorm_kernel(
    const int* __restrict__ src, const int* __restrict__ dst,
    const float* __restrict__ dinv, float* __restrict__ enorm, int E)
{
    int e = blockIdx.x * 256 + threadIdx.x;
    if (e >= E) return;
    enorm[e] = dinv[src[e]] * dinv[dst[e]];
}

// ---------- GEMM: tmp = A@W ; agg = tmp * dinv[row]^2 (self-loop init) ----------
// Block computes a 32-row x FO-col tile. W fully staged in LDS.
template<int FI, int FO>
__global__ __launch_bounds__(256) void gemm_agg_init_kernel(
    const float* __restrict__ A, const float* __restrict__ W,
    const float* __restrict__ dinv,
    float* __restrict__ tmp, float* __restrict__ agg, int N)
{
    constexpr int CT  = (FO >= 64) ? 64 : FO;  // col-threads
    constexpr int RT  = 256 / CT;              // row-thread groups
    constexpr int RPT = 32 / RT;               // rows per thread
    constexpr int CPT = FO / CT;               // cols per thread
    __shared__ float sW[FI * FO];
    __shared__ float sA[32][FI];
    const int t = threadIdx.x;
    for (int i = t; i < FI * FO; i += 256) sW[i] = W[i];
    const int row0 = blockIdx.x * 32;
    for (int i = t; i < 32 * FI; i += 256) {
        int r = i / FI, k = i % FI;
        int gr = row0 + r;
        sA[r][k] = (gr < N) ? A[(size_t)gr * FI + k] : 0.0f;
    }
    __syncthreads();
    const int c0 = t % CT;
    const int r0 = t / CT;
    float acc[RPT][CPT];
    #pragma unroll
    for (int rr = 0; rr < RPT; ++rr)
        #pragma unroll
        for (int cc = 0; cc < CPT; ++cc) acc[rr][cc] = 0.0f;
    for (int k = 0; k < FI; ++k) {
        float w[CPT];
        #pragma unroll
        for (int cc = 0; cc < CPT; ++cc) w[cc] = sW[k * FO + c0 + cc * CT];
        #pragma unroll
        for (int rr = 0; rr < RPT; ++rr) {
            float a = sA[r0 + rr * RT][k];
            #pragma unroll
            for (int cc = 0; cc < CPT; ++cc) acc[rr][cc] += a * w[cc];
        }
    }
    #pragma unroll
    for (int rr = 0; rr < RPT; ++rr) {
        int gr = row0 + r0 + rr * RT;
        if (gr >= N) continue;
        float dv = dinv[gr];
        float d2 = dv * dv;
        #pragma unroll
        for (int cc = 0; cc < CPT; ++cc) {
            size_t idx = (size_t)gr * FO + c0 + cc * CT;
            float v = acc[rr][cc];
            tmp[idx] = v;
            agg[idx] = v * d2;
        }
    }
}

// ---------- per-edge scatter: agg[dst] += tmp[src] * enorm ----------
template<int FO>
__global__ __launch_bounds__(256) void scatter_kernel(
    const int* __restrict__ src, const int* __restrict__ dst,
    const float* __restrict__ enorm, const float* __restrict__ tmp,
    float* __restrict__ agg, int E)
{
    constexpr int LPE = FO / 4;  // float4 lanes per edge
    int tid = blockIdx.x * 256 + threadIdx.x;
    if (tid >= E * LPE) return;
    int e = tid / LPE;
    int j = tid - e * LPE;
    int s = src[e], d = dst[e];
    float w = enorm[e];
    const float4 v = *reinterpret_cast<const float4*>(tmp + (size_t)s * FO + j * 4);
    float* dp = agg + (size_t)d * FO + j * 4;
    atomicAdd(dp + 0, v.x * w);
    atomicAdd(dp + 1, v.y * w);
    atomicAdd(dp + 2, v.z * w);
    atomicAdd(dp + 3, v.w * w);
}

// ---------- h = relu(agg + b), in-place capable ----------
template<int FO>
__global__ __launch_bounds__(256) void bias_relu_kernel(
    const float* __restrict__ agg, const float* __restrict__ b,
    float* __restrict__ h, int N)
{
    constexpr int LPR = FO / 4;
    int tid = blockIdx.x * 256 + threadIdx.x;
    if (tid >= N * LPR) return;
    int j = tid % LPR;
    float4 v = *reinterpret_cast<const float4*>(agg + (size_t)tid * 4);
    const float4 bb = *reinterpret_cast<const float4*>(b + j * 4);
    float4 o;
    o.x = fmaxf(v.x + bb.x, 0.0f);
    o.y = fmaxf(v.y + bb.y, 0.0f);
    o.z = fmaxf(v.z + bb.z, 0.0f);
    o.w = fmaxf(v.w + bb.w, 0.0f);
    *reinterpret_cast<float4*>(h + (size_t)tid * 4) = o;
}

// ---------- out = h @ Wl + bl  (32 lanes per node, shuffle reduce) ----------
__global__ __launch_bounds__(256) void final_linear_kernel(
    const float* __restrict__ h, const float* __restrict__ Wl,
    const float* __restrict__ bl, float* __restrict__ out, int N)
{
    int tid = blockIdx.x * 256 + threadIdx.x;
    int node = tid >> 5;
    int f = tid & 31;
    if (node >= N) return;
    float v = h[(size_t)node * 32 + f] * Wl[f];
    #pragma unroll
    for (int off = 16; off > 0; off >>= 1)
        v += __shfl_down(v, off, 32);
    if (f == 0) out[node] = v + bl[0];
}

extern "C" void kernel_launch(void* const* d_in, const int* in_sizes, int n_in,
                              void* d_out, int out_size, void* d_ws, size_t ws_size,
                              hipStream_t stream)
{
    const float* x  = (const float*)d_in[0];
    const int*   ei = (const int*)d_in[1];   // harness converts integer inputs to int32
    const float* W1 = (const float*)d_in[2];
    const float* b1 = (const float*)d_in[3];
    const float* W2 = (const float*)d_in[4];
    const float* b2 = (const float*)d_in[5];
    const float* W3 = (const float*)d_in[6];
    const float* b3 = (const float*)d_in[7];
    const float* Wl = (const float*)d_in[8];
    const float* bl = (const float*)d_in[9];
    float* out = (float*)d_out;

    const int N = in_sizes[0] / 128;
    const int E = in_sizes[1] / 2;

    const int* src = ei;        // edge_index row 0
    const int* dst = ei + E;    // edge_index row 1

    char* ws = (char*)d_ws;
    size_t off = 0;
    auto wsalloc = [&](size_t bytes) -> void* {
        void* p = ws + off;
        off = (off + bytes + 255) & ~(size_t)255;
        return p;
    };
    float* dinv  = (float*)wsalloc((size_t)N * 4);          // deg -> dinv in place
    float* enorm = (float*)wsalloc((size_t)E * 4);
    float* B1    = (float*)wsalloc((size_t)N * 128 * 4);
    float* B2    = (float*)wsalloc((size_t)N * 128 * 4);
    // total ws use: ~54.6 MB

    // ---- norm prep ----
    hipMemsetAsync(dinv, 0, (size_t)N * 4, stream);
    deg_kernel<<<CDIV(E, 256), 256, 0, stream>>>(dst, E, dinv);
    dinv_kernel<<<CDIV(N, 256), 256, 0, stream>>>(dinv, N);
    enorm_kernel<<<CDIV(E, 256), 256, 0, stream>>>(src, dst, dinv, enorm, E);

    // ---- layer 1: 128 -> 128 ----  tmp=B1, agg/h1=B2
    gemm_agg_init_kernel<128, 128><<<CDIV(N, 32), 256, 0, stream>>>(x, W1, dinv, B1, B2, N);
    scatter_kernel<128><<<CDIV(E * 32, 256), 256, 0, stream>>>(src, dst, enorm, B1, B2, E);
    bias_relu_kernel<128><<<CDIV(N * 32, 256), 256, 0, stream>>>(B2, b1, B2, N);

    // ---- layer 2: 128 -> 64 ----  tmp=B1[0:N*64], agg/h2=B1[N*64:]
    float* tmp2 = B1;
    float* h2   = B1 + (size_t)N * 64;
    gemm_agg_init_kernel<128, 64><<<CDIV(N, 32), 256, 0, stream>>>(B2, W2, dinv, tmp2, h2, N);
    scatter_kernel<64><<<CDIV(E * 16, 256), 256, 0, stream>>>(src, dst, enorm, tmp2, h2, E);
    bias_relu_kernel<64><<<CDIV(N * 16, 256), 256, 0, stream>>>(h2, b2, h2, N);

    // ---- layer 3: 64 -> 32 ----  tmp=B2[0:N*32], agg/h3=B2[N*32:]
    float* tmp3 = B2;
    float* h3   = B2 + (size_t)N * 32;
    gemm_agg_init_kernel<64, 32><<<CDIV(N, 32), 256, 0, stream>>>(h2, W3, dinv, tmp3, h3, N);
    scatter_kernel<32><<<CDIV(E * 8, 256), 256, 0, stream>>>(src, dst, enorm, tmp3, h3, E);
    bias_relu_kernel<32><<<CDIV(N * 8, 256), 256, 0, stream>>>(h3, b3, h3, N);

    // ---- final linear: 32 -> 1 ----
    final_linear_kernel<<<CDIV(N * 32, 256), 256, 0, stream>>>(h3, Wl, bl, out, N);
}

// Round 3
// 520.504 us; speedup vs baseline: 4.9030x; 4.9030x over previous
//
#include <hip/hip_runtime.h>
#include <math.h>

#define CDIV(a,b) (((a)+(b)-1)/(b))

// ---------- deg[dst]++ (int histogram) ----------
__global__ __launch_bounds__(256) void deg_kernel(
    const int* __restrict__ dst, int E, int* __restrict__ deg)
{
    int e = blockIdx.x * 256 + threadIdx.x;
    if (e >= E) return;
    atomicAdd(&deg[dst[e]], 1);
}

__global__ __launch_bounds__(256) void dinv_kernel(
    const int* __restrict__ deg, float* __restrict__ dinv, int N)
{
    int i = blockIdx.x * 256 + threadIdx.x;
    if (i >= N) return;
    dinv[i] = 1.0f / sqrtf((float)deg[i] + 1.0f);  // +1 for self-loop
}

// ---------- single-block exclusive scan: rowptr[0..N], rowptr[N]=E ----------
__global__ __launch_bounds__(1024) void scan_kernel(
    const int* __restrict__ deg, int* __restrict__ rowptr, int N)
{
    __shared__ int buf[1024];
    __shared__ int carry_s;
    const int t = threadIdx.x;
    if (t == 0) carry_s = 0;
    __syncthreads();
    for (int base = 0; base < N; base += 1024) {
        int i = base + t;
        int v = (i < N) ? deg[i] : 0;
        buf[t] = v;
        __syncthreads();
        for (int offs = 1; offs < 1024; offs <<= 1) {
            int add = (t >= offs) ? buf[t - offs] : 0;
            __syncthreads();
            buf[t] += add;
            __syncthreads();
        }
        int incl  = buf[t];
        int carry = carry_s;
        __syncthreads();
        if (t == 1023) carry_s = carry + incl;  // chunk total
        if (i < N) rowptr[i] = carry + incl - v;
        __syncthreads();
    }
    if (t == 0) rowptr[N] = carry_s;
}

// ---------- scatter edges into CSR slots (order within node nondeterministic) ----------
__global__ __launch_bounds__(256) void csr_build_kernel(
    const int* __restrict__ src, const int* __restrict__ dst,
    const float* __restrict__ dinv, int* __restrict__ cursor,
    int* __restrict__ csr_src, float* __restrict__ csr_w, int E)
{
    int e = blockIdx.x * 256 + threadIdx.x;
    if (e >= E) return;
    int s = src[e], d = dst[e];
    int pos = atomicAdd(&cursor[d], 1);
    csr_src[pos] = s;
    csr_w[pos]   = dinv[s] * dinv[d];
}

// ---------- GEMM: tmp = A@W (W staged in LDS) ----------
template<int FI, int FO>
__global__ __launch_bounds__(256) void gemm_kernel(
    const float* __restrict__ A, const float* __restrict__ W,
    float* __restrict__ tmp, int N)
{
    constexpr int CT  = (FO >= 64) ? 64 : FO;  // col-threads
    constexpr int RT  = 256 / CT;              // row-thread groups
    constexpr int RPT = 32 / RT;               // rows per thread
    constexpr int CPT = FO / CT;               // cols per thread
    __shared__ float sW[FI * FO];
    __shared__ float sA[32][FI];
    const int t = threadIdx.x;
    for (int i = t; i < FI * FO; i += 256) sW[i] = W[i];
    const int row0 = blockIdx.x * 32;
    for (int i = t; i < 32 * FI; i += 256) {
        int r = i / FI, k = i % FI;
        int gr = row0 + r;
        sA[r][k] = (gr < N) ? A[(size_t)gr * FI + k] : 0.0f;
    }
    __syncthreads();
    const int c0 = t % CT;
    const int r0 = t / CT;
    float acc[RPT][CPT];
    #pragma unroll
    for (int rr = 0; rr < RPT; ++rr)
        #pragma unroll
        for (int cc = 0; cc < CPT; ++cc) acc[rr][cc] = 0.0f;
    for (int k = 0; k < FI; ++k) {
        float w[CPT];
        #pragma unroll
        for (int cc = 0; cc < CPT; ++cc) w[cc] = sW[k * FO + c0 + cc * CT];
        #pragma unroll
        for (int rr = 0; rr < RPT; ++rr) {
            float a = sA[r0 + rr * RT][k];
            #pragma unroll
            for (int cc = 0; cc < CPT; ++cc) acc[rr][cc] += a * w[cc];
        }
    }
    #pragma unroll
    for (int rr = 0; rr < RPT; ++rr) {
        int gr = row0 + r0 + rr * RT;
        if (gr >= N) continue;
        #pragma unroll
        for (int cc = 0; cc < CPT; ++cc)
            tmp[(size_t)gr * FO + c0 + cc * CT] = acc[rr][cc];
    }
}

// ---------- gather-side aggregation + self-loop + bias + ReLU ----------
// One node per 64-lane wave (FO=128: 2 floats/lane; FO=64: 1; FO=32: 2 nodes/wave).
template<int FO, bool RELU>
__global__ __launch_bounds__(256) void agg_kernel(
    const int* __restrict__ rowptr, const int* __restrict__ csr_src,
    const float* __restrict__ csr_w, const float* __restrict__ dinv,
    const float* __restrict__ tmp, const float* __restrict__ b,
    float* __restrict__ h, int N)
{
    constexpr int GPW = (FO == 32) ? 2 : 1;   // node-groups per wave
    constexpr int GL  = 64 / GPW;             // lanes per group
    constexpr int FPL = FO / GL;              // floats per lane (2 for FO=128, else 1)
    const int wid  = (blockIdx.x * 256 + threadIdx.x) >> 6;
    const int lane = threadIdx.x & 63;
    const int g    = lane / GL;
    const int fl   = lane % GL;
    const int node = wid * GPW + g;
    if (node >= N) return;

    float acc[FPL];
    #pragma unroll
    for (int q = 0; q < FPL; ++q) acc[q] = 0.0f;

    const int jb = rowptr[node], je = rowptr[node + 1];
    for (int j = jb; j < je; ++j) {
        int   s = csr_src[j];           // broadcast within group
        float w = csr_w[j];
        const float* p = tmp + (size_t)s * FO + fl * FPL;
        #pragma unroll
        for (int q = 0; q < FPL; ++q) acc[q] += p[q] * w;
    }
    // self-loop
    float dv = dinv[node];
    float d2 = dv * dv;
    const float* ps = tmp + (size_t)node * FO + fl * FPL;
    #pragma unroll
    for (int q = 0; q < FPL; ++q) acc[q] += ps[q] * d2;

    float* o = h + (size_t)node * FO + fl * FPL;
    #pragma unroll
    for (int q = 0; q < FPL; ++q) {
        float v = acc[q] + b[fl * FPL + q];
        o[q] = RELU ? fmaxf(v, 0.0f) : v;
    }
}

// ---------- out = h @ Wl + bl  (32 lanes per node, shuffle reduce) ----------
__global__ __launch_bounds__(256) void final_linear_kernel(
    const float* __restrict__ h, const float* __restrict__ Wl,
    const float* __restrict__ bl, float* __restrict__ out, int N)
{
    int tid = blockIdx.x * 256 + threadIdx.x;
    int node = tid >> 5;
    int f = tid & 31;
    if (node >= N) return;
    float v = h[(size_t)node * 32 + f] * Wl[f];
    #pragma unroll
    for (int off = 16; off > 0; off >>= 1)
        v += __shfl_down(v, off, 32);
    if (f == 0) out[node] = v + bl[0];
}

extern "C" void kernel_launch(void* const* d_in, const int* in_sizes, int n_in,
                              void* d_out, int out_size, void* d_ws, size_t ws_size,
                              hipStream_t stream)
{
    const float* x  = (const float*)d_in[0];
    const int*   ei = (const int*)d_in[1];   // int inputs arrive as int32
    const float* W1 = (const float*)d_in[2];
    const float* b1 = (const float*)d_in[3];
    const float* W2 = (const float*)d_in[4];
    const float* b2 = (const float*)d_in[5];
    const float* W3 = (const float*)d_in[6];
    const float* b3 = (const float*)d_in[7];
    const float* Wl = (const float*)d_in[8];
    const float* bl = (const float*)d_in[9];
    float* out = (float*)d_out;

    const int N = in_sizes[0] / 128;
    const int E = in_sizes[1] / 2;

    const int* src = ei;        // edge_index row 0
    const int* dst = ei + E;    // edge_index row 1

    char* ws = (char*)d_ws;
    size_t off = 0;
    auto wsalloc = [&](size_t bytes) -> void* {
        void* p = ws + off;
        off = (off + bytes + 255) & ~(size_t)255;
        return p;
    };
    int*   deg     = (int*)  wsalloc((size_t)N * 4);
    float* dinv    = (float*)wsalloc((size_t)N * 4);
    int*   rowptr  = (int*)  wsalloc((size_t)(N + 1) * 4);
    int*   cursor  = (int*)  wsalloc((size_t)N * 4);
    int*   csr_src = (int*)  wsalloc((size_t)E * 4);
    float* csr_w   = (float*)wsalloc((size_t)E * 4);
    float* B1      = (float*)wsalloc((size_t)N * 128 * 4);  // tmp
    float* B2      = (float*)wsalloc((size_t)N * 128 * 4);  // h
    // total ws use: ~58.5 MB

    // ---- CSR build ----
    hipMemsetAsync(deg, 0, (size_t)N * 4, stream);
    deg_kernel<<<CDIV(E, 256), 256, 0, stream>>>(dst, E, deg);
    dinv_kernel<<<CDIV(N, 256), 256, 0, stream>>>(deg, dinv, N);
    scan_kernel<<<1, 1024, 0, stream>>>(deg, rowptr, N);
    hipMemcpyAsync(cursor, rowptr, (size_t)N * 4, hipMemcpyDeviceToDevice, stream);
    csr_build_kernel<<<CDIV(E, 256), 256, 0, stream>>>(src, dst, dinv, cursor,
                                                       csr_src, csr_w, E);

    // ---- layer 1: 128 -> 128 ----
    gemm_kernel<128, 128><<<CDIV(N, 32), 256, 0, stream>>>(x, W1, B1, N);
    agg_kernel<128, true><<<CDIV(N, 4), 256, 0, stream>>>(rowptr, csr_src, csr_w,
                                                          dinv, B1, b1, B2, N);

    // ---- layer 2: 128 -> 64 ----
    gemm_kernel<128, 64><<<CDIV(N, 32), 256, 0, stream>>>(B2, W2, B1, N);
    agg_kernel<64, true><<<CDIV(N, 4), 256, 0, stream>>>(rowptr, csr_src, csr_w,
                                                         dinv, B1, b2, B2, N);

    // ---- layer 3: 64 -> 32 ----
    gemm_kernel<64, 32><<<CDIV(N, 32), 256, 0, stream>>>(B2, W3, B1, N);
    agg_kernel<32, true><<<CDIV(N, 8), 256, 0, stream>>>(rowptr, csr_src, csr_w,
                                                         dinv, B1, b3, B2, N);

    // ---- final linear: 32 -> 1 ----
    final_linear_kernel<<<CDIV(N * 32, 256), 256, 0, stream>>>(B2, Wl, bl, out, N);
}

// Round 4
// 349.907 us; speedup vs baseline: 7.2934x; 1.4876x over previous
//
#include <hip/hip_runtime.h>
#include <math.h>

#define CDIV(a,b) (((a)+(b)-1)/(b))

// ---------- deg[dst]++ (int histogram) ----------
__global__ __launch_bounds__(256) void deg_kernel(
    const int* __restrict__ dst, int E, int* __restrict__ deg)
{
    int e = blockIdx.x * 256 + threadIdx.x;
    if (e >= E) return;
    atomicAdd(&deg[dst[e]], 1);
}

__global__ __launch_bounds__(256) void dinv_kernel(
    const int* __restrict__ deg, float* __restrict__ dinv, int N)
{
    int i = blockIdx.x * 256 + threadIdx.x;
    if (i >= N) return;
    dinv[i] = 1.0f / sqrtf((float)deg[i] + 1.0f);  // +1 for self-loop
}

// ---------- hierarchical exclusive scan ----------
// Pass 1: per-block (1024-wide) exclusive scan + block sums
__global__ __launch_bounds__(1024) void block_scan_kernel(
    const int* __restrict__ deg, int* __restrict__ excl,
    int* __restrict__ bsums, int N)
{
    __shared__ int buf[1024];
    const int t = threadIdx.x;
    const int i = blockIdx.x * 1024 + t;
    int v = (i < N) ? deg[i] : 0;
    buf[t] = v;
    __syncthreads();
    for (int offs = 1; offs < 1024; offs <<= 1) {
        int add = (t >= offs) ? buf[t - offs] : 0;
        __syncthreads();
        buf[t] += add;
        __syncthreads();
    }
    if (i < N) excl[i] = buf[t] - v;
    if (t == 1023) bsums[blockIdx.x] = buf[t];
}

// Pass 2: exclusive scan of block sums (nb <= 1024), single small block
__global__ __launch_bounds__(1024) void scan_bsums_kernel(
    int* __restrict__ bsums, int nb)
{
    __shared__ int buf[1024];
    const int t = threadIdx.x;
    int v = (t < nb) ? bsums[t] : 0;
    buf[t] = v;
    __syncthreads();
    for (int offs = 1; offs < 1024; offs <<= 1) {
        int add = (t >= offs) ? buf[t - offs] : 0;
        __syncthreads();
        buf[t] += add;
        __syncthreads();
    }
    if (t < nb) bsums[t] = buf[t] - v;  // exclusive
}

// Pass 3: add block offsets; also materialize cursor (saves a D2D memcpy)
__global__ __launch_bounds__(256) void add_offsets_kernel(
    int* __restrict__ rowptr, int* __restrict__ cursor,
    const int* __restrict__ bsums, int N, int E)
{
    int i = blockIdx.x * 256 + threadIdx.x;
    if (i < N) {
        int v = rowptr[i] + bsums[i >> 10];
        rowptr[i] = v;
        cursor[i] = v;
    }
    if (i == N) rowptr[N] = E;
}

// ---------- scatter edges into CSR slots ----------
__global__ __launch_bounds__(256) void csr_build_kernel(
    const int* __restrict__ src, const int* __restrict__ dst,
    int* __restrict__ cursor, int* __restrict__ csr_src, int E)
{
    int e = blockIdx.x * 256 + threadIdx.x;
    if (e >= E) return;
    int pos = atomicAdd(&cursor[dst[e]], 1);
    csr_src[pos] = src[e];
}

// ---------- GEMM: tmp = A@W (W staged in LDS) ----------
template<int FI, int FO>
__global__ __launch_bounds__(256) void gemm_kernel(
    const float* __restrict__ A, const float* __restrict__ W,
    float* __restrict__ tmp, int N)
{
    constexpr int CT  = (FO >= 64) ? 64 : FO;  // col-threads
    constexpr int RT  = 256 / CT;              // row-thread groups
    constexpr int RPT = 32 / RT;               // rows per thread
    constexpr int CPT = FO / CT;               // cols per thread
    __shared__ float sW[FI * FO];
    __shared__ float sA[32][FI];
    const int t = threadIdx.x;
    for (int i = t; i < FI * FO; i += 256) sW[i] = W[i];
    const int row0 = blockIdx.x * 32;
    for (int i = t; i < 32 * FI; i += 256) {
        int r = i / FI, k = i % FI;
        int gr = row0 + r;
        sA[r][k] = (gr < N) ? A[(size_t)gr * FI + k] : 0.0f;
    }
    __syncthreads();
    const int c0 = t % CT;
    const int r0 = t / CT;
    float acc[RPT][CPT];
    #pragma unroll
    for (int rr = 0; rr < RPT; ++rr)
        #pragma unroll
        for (int cc = 0; cc < CPT; ++cc) acc[rr][cc] = 0.0f;
    for (int k = 0; k < FI; ++k) {
        float w[CPT];
        #pragma unroll
        for (int cc = 0; cc < CPT; ++cc) w[cc] = sW[k * FO + c0 + cc * CT];
        #pragma unroll
        for (int rr = 0; rr < RPT; ++rr) {
            float a = sA[r0 + rr * RT][k];
            #pragma unroll
            for (int cc = 0; cc < CPT; ++cc) acc[rr][cc] += a * w[cc];
        }
    }
    #pragma unroll
    for (int rr = 0; rr < RPT; ++rr) {
        int gr = row0 + r0 + rr * RT;
        if (gr >= N) continue;
        #pragma unroll
        for (int cc = 0; cc < CPT; ++cc)
            tmp[(size_t)gr * FO + c0 + cc * CT] = acc[rr][cc];
    }
}

// ---------- gather-side aggregation + self-loop + bias + ReLU ----------
// One node per 64-lane wave (FO=128: float2/lane; FO=64: 1; FO=32: 2 nodes/wave).
// Edge loop unrolled x4 with independent accumulators for memory-level parallelism.
template<int FO, bool RELU>
__global__ __launch_bounds__(256) void agg_kernel(
    const int* __restrict__ rowptr, const int* __restrict__ csr_src,
    const float* __restrict__ dinv, const float* __restrict__ tmp,
    const float* __restrict__ b, float* __restrict__ h, int N)
{
    constexpr int GPW = (FO == 32) ? 2 : 1;   // node-groups per wave
    constexpr int GL  = 64 / GPW;             // lanes per group
    constexpr int FPL = FO / GL;              // floats per lane
    const int wid  = (blockIdx.x * 256 + threadIdx.x) >> 6;
    const int lane = threadIdx.x & 63;
    const int g    = lane / GL;
    const int fl   = lane % GL;
    const int node = wid * GPW + g;
    if (node >= N) return;

    float acc0[FPL], acc1[FPL], acc2[FPL], acc3[FPL];
    #pragma unroll
    for (int q = 0; q < FPL; ++q) { acc0[q] = 0.f; acc1[q] = 0.f; acc2[q] = 0.f; acc3[q] = 0.f; }

    const float dvd = dinv[node];
    const int jb = rowptr[node], je = rowptr[node + 1];
    int j = jb;
    for (; j + 4 <= je; j += 4) {
        int s0 = csr_src[j + 0];
        int s1 = csr_src[j + 1];
        int s2 = csr_src[j + 2];
        int s3 = csr_src[j + 3];
        float w0 = dinv[s0] * dvd;
        float w1 = dinv[s1] * dvd;
        float w2 = dinv[s2] * dvd;
        float w3 = dinv[s3] * dvd;
        const float* p0 = tmp + (size_t)s0 * FO + fl * FPL;
        const float* p1 = tmp + (size_t)s1 * FO + fl * FPL;
        const float* p2 = tmp + (size_t)s2 * FO + fl * FPL;
        const float* p3 = tmp + (size_t)s3 * FO + fl * FPL;
        #pragma unroll
        for (int q = 0; q < FPL; ++q) {
            acc0[q] += p0[q] * w0;
            acc1[q] += p1[q] * w1;
            acc2[q] += p2[q] * w2;
            acc3[q] += p3[q] * w3;
        }
    }
    for (; j < je; ++j) {
        int s = csr_src[j];
        float w = dinv[s] * dvd;
        const float* p = tmp + (size_t)s * FO + fl * FPL;
        #pragma unroll
        for (int q = 0; q < FPL; ++q) acc0[q] += p[q] * w;
    }
    // self-loop
    const float* ps = tmp + (size_t)node * FO + fl * FPL;
    const float d2 = dvd * dvd;
    #pragma unroll
    for (int q = 0; q < FPL; ++q) acc1[q] += ps[q] * d2;

    float* o = h + (size_t)node * FO + fl * FPL;
    #pragma unroll
    for (int q = 0; q < FPL; ++q) {
        float v = ((acc0[q] + acc1[q]) + (acc2[q] + acc3[q])) + b[fl * FPL + q];
        o[q] = RELU ? fmaxf(v, 0.0f) : v;
    }
}

// ---------- out = h @ Wl + bl  (32 lanes per node, shuffle reduce) ----------
__global__ __launch_bounds__(256) void final_linear_kernel(
    const float* __restrict__ h, const float* __restrict__ Wl,
    const float* __restrict__ bl, float* __restrict__ out, int N)
{
    int tid = blockIdx.x * 256 + threadIdx.x;
    int node = tid >> 5;
    int f = tid & 31;
    if (node >= N) return;
    float v = h[(size_t)node * 32 + f] * Wl[f];
    #pragma unroll
    for (int off = 16; off > 0; off >>= 1)
        v += __shfl_down(v, off, 32);
    if (f == 0) out[node] = v + bl[0];
}

extern "C" void kernel_launch(void* const* d_in, const int* in_sizes, int n_in,
                              void* d_out, int out_size, void* d_ws, size_t ws_size,
                              hipStream_t stream)
{
    const float* x  = (const float*)d_in[0];
    const int*   ei = (const int*)d_in[1];   // int inputs arrive as int32
    const float* W1 = (const float*)d_in[2];
    const float* b1 = (const float*)d_in[3];
    const float* W2 = (const float*)d_in[4];
    const float* b2 = (const float*)d_in[5];
    const float* W3 = (const float*)d_in[6];
    const float* b3 = (const float*)d_in[7];
    const float* Wl = (const float*)d_in[8];
    const float* bl = (const float*)d_in[9];
    float* out = (float*)d_out;

    const int N = in_sizes[0] / 128;
    const int E = in_sizes[1] / 2;

    const int* src = ei;        // edge_index row 0
    const int* dst = ei + E;    // edge_index row 1

    char* ws = (char*)d_ws;
    size_t off = 0;
    auto wsalloc = [&](size_t bytes) -> void* {
        void* p = ws + off;
        off = (off + bytes + 255) & ~(size_t)255;
        return p;
    };
    const int NB = CDIV(N, 1024);
    int*   deg     = (int*)  wsalloc((size_t)N * 4);
    float* dinv    = (float*)wsalloc((size_t)N * 4);
    int*   rowptr  = (int*)  wsalloc((size_t)(N + 1) * 4);
    int*   cursor  = (int*)  wsalloc((size_t)N * 4);
    int*   bsums   = (int*)  wsalloc((size_t)NB * 4);
    int*   csr_src = (int*)  wsalloc((size_t)E * 4);
    float* B1      = (float*)wsalloc((size_t)N * 128 * 4);  // tmp
    float* B2      = (float*)wsalloc((size_t)N * 128 * 4);  // h
    // total ws use: ~55 MB

    // ---- CSR build ----
    hipMemsetAsync(deg, 0, (size_t)N * 4, stream);
    deg_kernel<<<CDIV(E, 256), 256, 0, stream>>>(dst, E, deg);
    dinv_kernel<<<CDIV(N, 256), 256, 0, stream>>>(deg, dinv, N);
    block_scan_kernel<<<NB, 1024, 0, stream>>>(deg, rowptr, bsums, N);
    scan_bsums_kernel<<<1, 1024, 0, stream>>>(bsums, NB);
    add_offsets_kernel<<<CDIV(N + 1, 256), 256, 0, stream>>>(rowptr, cursor, bsums, N, E);
    csr_build_kernel<<<CDIV(E, 256), 256, 0, stream>>>(src, dst, cursor, csr_src, E);

    // ---- layer 1: 128 -> 128 ----
    gemm_kernel<128, 128><<<CDIV(N, 32), 256, 0, stream>>>(x, W1, B1, N);
    agg_kernel<128, true><<<CDIV(N, 4), 256, 0, stream>>>(rowptr, csr_src, dinv, B1, b1, B2, N);

    // ---- layer 2: 128 -> 64 ----
    gemm_kernel<128, 64><<<CDIV(N, 32), 256, 0, stream>>>(B2, W2, B1, N);
    agg_kernel<64, true><<<CDIV(N, 4), 256, 0, stream>>>(rowptr, csr_src, dinv, B1, b2, B2, N);

    // ---- layer 3: 64 -> 32 ----
    gemm_kernel<64, 32><<<CDIV(N, 32), 256, 0, stream>>>(B2, W3, B1, N);
    agg_kernel<32, true><<<CDIV(N, 8), 256, 0, stream>>>(rowptr, csr_src, dinv, B1, b3, B2, N);

    // ---- final linear: 32 -> 1 ----
    final_linear_kernel<<<CDIV(N * 32, 256), 256, 0, stream>>>(B2, Wl, bl, out, N);
}

// Round 5
// 328.328 us; speedup vs baseline: 7.7728x; 1.0657x over previous
//
#include <hip/hip_runtime.h>
#include <math.h>

#define CDIV(a,b) (((a)+(b)-1)/(b))

// ---------- deg[dst]++ (int histogram) ----------
__global__ __launch_bounds__(256) void deg_kernel(
    const int* __restrict__ dst, int E, int* __restrict__ deg)
{
    int e = blockIdx.x * 256 + threadIdx.x;
    if (e >= E) return;
    atomicAdd(&deg[dst[e]], 1);
}

__global__ __launch_bounds__(256) void dinv_kernel(
    const int* __restrict__ deg, float* __restrict__ dinv, int N)
{
    int i = blockIdx.x * 256 + threadIdx.x;
    if (i >= N) return;
    dinv[i] = 1.0f / sqrtf((float)deg[i] + 1.0f);  // +1 for self-loop
}

// ---------- hierarchical exclusive scan ----------
__global__ __launch_bounds__(1024) void block_scan_kernel(
    const int* __restrict__ deg, int* __restrict__ excl,
    int* __restrict__ bsums, int N)
{
    __shared__ int buf[1024];
    const int t = threadIdx.x;
    const int i = blockIdx.x * 1024 + t;
    int v = (i < N) ? deg[i] : 0;
    buf[t] = v;
    __syncthreads();
    for (int offs = 1; offs < 1024; offs <<= 1) {
        int add = (t >= offs) ? buf[t - offs] : 0;
        __syncthreads();
        buf[t] += add;
        __syncthreads();
    }
    if (i < N) excl[i] = buf[t] - v;
    if (t == 1023) bsums[blockIdx.x] = buf[t];
}

__global__ __launch_bounds__(1024) void scan_bsums_kernel(
    int* __restrict__ bsums, int nb)
{
    __shared__ int buf[1024];
    const int t = threadIdx.x;
    int v = (t < nb) ? bsums[t] : 0;
    buf[t] = v;
    __syncthreads();
    for (int offs = 1; offs < 1024; offs <<= 1) {
        int add = (t >= offs) ? buf[t - offs] : 0;
        __syncthreads();
        buf[t] += add;
        __syncthreads();
    }
    if (t < nb) bsums[t] = buf[t] - v;  // exclusive
}

__global__ __launch_bounds__(256) void add_offsets_kernel(
    int* __restrict__ rowptr, int* __restrict__ cursor,
    const int* __restrict__ bsums, int N, int E)
{
    int i = blockIdx.x * 256 + threadIdx.x;
    if (i < N) {
        int v = rowptr[i] + bsums[i >> 10];
        rowptr[i] = v;
        cursor[i] = v;
    }
    if (i == N) rowptr[N] = E;
}

// ---------- scatter edges into CSR slots ----------
__global__ __launch_bounds__(256) void csr_build_kernel(
    const int* __restrict__ src, const int* __restrict__ dst,
    int* __restrict__ cursor, int* __restrict__ csr_src, int E)
{
    int e = blockIdx.x * 256 + threadIdx.x;
    if (e >= E) return;
    int pos = atomicAdd(&cursor[dst[e]], 1);
    csr_src[pos] = src[e];
}

// ---------- GEMM: tmp = A@W ----------
// 64-row x FO-col tile, K tiled by 32, all LDS reads b128, sA padded (+4).
template<int FI, int FO>
__global__ __launch_bounds__(256) void gemm_kernel(
    const float* __restrict__ A, const float* __restrict__ W,
    float* __restrict__ tmp, int N)
{
    constexpr int ROWS = 64;
    constexpr int KT   = 32;
    constexpr int CT   = FO / 4;      // col-thread groups (float4 each)
    constexpr int RT   = 256 / CT;    // row-thread groups
    constexpr int RPT  = ROWS / RT;   // rows per thread
    constexpr int NCH  = FI / KT;     // k-chunks

    __shared__ float sA[ROWS][KT + 4];
    __shared__ float sW[KT][FO];

    const int t    = threadIdx.x;
    const int row0 = blockIdx.x * ROWS;
    const int c0   = (t % CT) * 4;
    const int r0   = t / CT;          // row base; rows r0 + rr*RT

    float acc[RPT][4];
    #pragma unroll
    for (int rr = 0; rr < RPT; ++rr)
        #pragma unroll
        for (int c = 0; c < 4; ++c) acc[rr][c] = 0.0f;

    for (int kc = 0; kc < NCH; ++kc) {
        // stage sA: ROWS x KT floats = ROWS*KT/4 float4s
        #pragma unroll
        for (int it = 0; it < (ROWS * KT / 4) / 256; ++it) {
            int idx = it * 256 + t;
            int r  = idx / (KT / 4);
            int kq = idx % (KT / 4);
            int gr = row0 + r;
            float4 v = make_float4(0.f, 0.f, 0.f, 0.f);
            if (gr < N)
                v = *reinterpret_cast<const float4*>(A + (size_t)gr * FI + kc * KT + kq * 4);
            *reinterpret_cast<float4*>(&sA[r][kq * 4]) = v;
        }
        // stage sW: KT x FO floats
        #pragma unroll
        for (int it = 0; it < (KT * FO / 4) / 256; ++it) {
            int idx = it * 256 + t;
            int kk = idx / (FO / 4);
            int cq = idx % (FO / 4);
            *reinterpret_cast<float4*>(&sW[kk][cq * 4]) =
                *reinterpret_cast<const float4*>(W + (size_t)(kc * KT + kk) * FO + cq * 4);
        }
        __syncthreads();

        #pragma unroll
        for (int k4 = 0; k4 < KT / 4; ++k4) {
            float4 w4[4];
            #pragma unroll
            for (int j = 0; j < 4; ++j)
                w4[j] = *reinterpret_cast<const float4*>(&sW[k4 * 4 + j][c0]);
            float4 a4[RPT];
            #pragma unroll
            for (int rr = 0; rr < RPT; ++rr)
                a4[rr] = *reinterpret_cast<const float4*>(&sA[r0 + rr * RT][k4 * 4]);
            #pragma unroll
            for (int rr = 0; rr < RPT; ++rr) {
                acc[rr][0] += a4[rr].x * w4[0].x + a4[rr].y * w4[1].x + a4[rr].z * w4[2].x + a4[rr].w * w4[3].x;
                acc[rr][1] += a4[rr].x * w4[0].y + a4[rr].y * w4[1].y + a4[rr].z * w4[2].y + a4[rr].w * w4[3].y;
                acc[rr][2] += a4[rr].x * w4[0].z + a4[rr].y * w4[1].z + a4[rr].z * w4[2].z + a4[rr].w * w4[3].z;
                acc[rr][3] += a4[rr].x * w4[0].w + a4[rr].y * w4[1].w + a4[rr].z * w4[2].w + a4[rr].w * w4[3].w;
            }
        }
        __syncthreads();
    }

    #pragma unroll
    for (int rr = 0; rr < RPT; ++rr) {
        int gr = row0 + r0 + rr * RT;
        if (gr >= N) continue;
        *reinterpret_cast<float4*>(tmp + (size_t)gr * FO + c0) =
            make_float4(acc[rr][0], acc[rr][1], acc[rr][2], acc[rr][3]);
    }
}

// ---------- gather-side aggregation + self-loop + bias + ReLU ----------
template<int FO, bool RELU>
__global__ __launch_bounds__(256) void agg_kernel(
    const int* __restrict__ rowptr, const int* __restrict__ csr_src,
    const float* __restrict__ dinv, const float* __restrict__ tmp,
    const float* __restrict__ b, float* __restrict__ h, int N)
{
    constexpr int GPW = (FO == 32) ? 2 : 1;   // node-groups per wave
    constexpr int GL  = 64 / GPW;             // lanes per group
    constexpr int FPL = FO / GL;              // floats per lane
    const int wid  = (blockIdx.x * 256 + threadIdx.x) >> 6;
    const int lane = threadIdx.x & 63;
    const int g    = lane / GL;
    const int fl   = lane % GL;
    const int node = wid * GPW + g;
    if (node >= N) return;

    float acc0[FPL], acc1[FPL], acc2[FPL], acc3[FPL];
    #pragma unroll
    for (int q = 0; q < FPL; ++q) { acc0[q] = 0.f; acc1[q] = 0.f; acc2[q] = 0.f; acc3[q] = 0.f; }

    const float dvd = dinv[node];
    const int jb = rowptr[node], je = rowptr[node + 1];
    int j = jb;
    for (; j + 4 <= je; j += 4) {
        int s0 = csr_src[j + 0];
        int s1 = csr_src[j + 1];
        int s2 = csr_src[j + 2];
        int s3 = csr_src[j + 3];
        float w0 = dinv[s0] * dvd;
        float w1 = dinv[s1] * dvd;
        float w2 = dinv[s2] * dvd;
        float w3 = dinv[s3] * dvd;
        const float* p0 = tmp + (size_t)s0 * FO + fl * FPL;
        const float* p1 = tmp + (size_t)s1 * FO + fl * FPL;
        const float* p2 = tmp + (size_t)s2 * FO + fl * FPL;
        const float* p3 = tmp + (size_t)s3 * FO + fl * FPL;
        #pragma unroll
        for (int q = 0; q < FPL; ++q) {
            acc0[q] += p0[q] * w0;
            acc1[q] += p1[q] * w1;
            acc2[q] += p2[q] * w2;
            acc3[q] += p3[q] * w3;
        }
    }
    for (; j < je; ++j) {
        int s = csr_src[j];
        float w = dinv[s] * dvd;
        const float* p = tmp + (size_t)s * FO + fl * FPL;
        #pragma unroll
        for (int q = 0; q < FPL; ++q) acc0[q] += p[q] * w;
    }
    // self-loop
    const float* ps = tmp + (size_t)node * FO + fl * FPL;
    const float d2 = dvd * dvd;
    #pragma unroll
    for (int q = 0; q < FPL; ++q) acc1[q] += ps[q] * d2;

    float* o = h + (size_t)node * FO + fl * FPL;
    #pragma unroll
    for (int q = 0; q < FPL; ++q) {
        float v = ((acc0[q] + acc1[q]) + (acc2[q] + acc3[q])) + b[fl * FPL + q];
        o[q] = RELU ? fmaxf(v, 0.0f) : v;
    }
}

// ---------- out = h @ Wl + bl  (32 lanes per node, shuffle reduce) ----------
__global__ __launch_bounds__(256) void final_linear_kernel(
    const float* __restrict__ h, const float* __restrict__ Wl,
    const float* __restrict__ bl, float* __restrict__ out, int N)
{
    int tid = blockIdx.x * 256 + threadIdx.x;
    int node = tid >> 5;
    int f = tid & 31;
    if (node >= N) return;
    float v = h[(size_t)node * 32 + f] * Wl[f];
    #pragma unroll
    for (int off = 16; off > 0; off >>= 1)
        v += __shfl_down(v, off, 32);
    if (f == 0) out[node] = v + bl[0];
}

extern "C" void kernel_launch(void* const* d_in, const int* in_sizes, int n_in,
                              void* d_out, int out_size, void* d_ws, size_t ws_size,
                              hipStream_t stream)
{
    const float* x  = (const float*)d_in[0];
    const int*   ei = (const int*)d_in[1];   // int inputs arrive as int32
    const float* W1 = (const float*)d_in[2];
    const float* b1 = (const float*)d_in[3];
    const float* W2 = (const float*)d_in[4];
    const float* b2 = (const float*)d_in[5];
    const float* W3 = (const float*)d_in[6];
    const float* b3 = (const float*)d_in[7];
    const float* Wl = (const float*)d_in[8];
    const float* bl = (const float*)d_in[9];
    float* out = (float*)d_out;

    const int N = in_sizes[0] / 128;
    const int E = in_sizes[1] / 2;

    const int* src = ei;        // edge_index row 0
    const int* dst = ei + E;    // edge_index row 1

    char* ws = (char*)d_ws;
    size_t off = 0;
    auto wsalloc = [&](size_t bytes) -> void* {
        void* p = ws + off;
        off = (off + bytes + 255) & ~(size_t)255;
        return p;
    };
    const int NB = CDIV(N, 1024);
    int*   deg     = (int*)  wsalloc((size_t)N * 4);
    float* dinv    = (float*)wsalloc((size_t)N * 4);
    int*   rowptr  = (int*)  wsalloc((size_t)(N + 1) * 4);
    int*   cursor  = (int*)  wsalloc((size_t)N * 4);
    int*   bsums   = (int*)  wsalloc((size_t)NB * 4);
    int*   csr_src = (int*)  wsalloc((size_t)E * 4);
    float* B1      = (float*)wsalloc((size_t)N * 128 * 4);  // tmp
    float* B2      = (float*)wsalloc((size_t)N * 128 * 4);  // h
    // total ws use: ~55 MB

    // ---- CSR build ----
    hipMemsetAsync(deg, 0, (size_t)N * 4, stream);
    deg_kernel<<<CDIV(E, 256), 256, 0, stream>>>(dst, E, deg);
    dinv_kernel<<<CDIV(N, 256), 256, 0, stream>>>(deg, dinv, N);
    block_scan_kernel<<<NB, 1024, 0, stream>>>(deg, rowptr, bsums, N);
    scan_bsums_kernel<<<1, 1024, 0, stream>>>(bsums, NB);
    add_offsets_kernel<<<CDIV(N + 1, 256), 256, 0, stream>>>(rowptr, cursor, bsums, N, E);
    csr_build_kernel<<<CDIV(E, 256), 256, 0, stream>>>(src, dst, cursor, csr_src, E);

    // ---- layer 1: 128 -> 128 ----
    gemm_kernel<128, 128><<<CDIV(N, 64), 256, 0, stream>>>(x, W1, B1, N);
    agg_kernel<128, true><<<CDIV(N, 4), 256, 0, stream>>>(rowptr, csr_src, dinv, B1, b1, B2, N);

    // ---- layer 2: 128 -> 64 ----
    gemm_kernel<128, 64><<<CDIV(N, 64), 256, 0, stream>>>(B2, W2, B1, N);
    agg_kernel<64, true><<<CDIV(N, 4), 256, 0, stream>>>(rowptr, csr_src, dinv, B1, b2, B2, N);

    // ---- layer 3: 64 -> 32 ----
    gemm_kernel<64, 32><<<CDIV(N, 64), 256, 0, stream>>>(B2, W3, B1, N);
    agg_kernel<32, true><<<CDIV(N, 8), 256, 0, stream>>>(rowptr, csr_src, dinv, B1, b3, B2, N);

    // ---- final linear: 32 -> 1 ----
    final_linear_kernel<<<CDIV(N * 32, 256), 256, 0, stream>>>(B2, Wl, bl, out, N);
}

// Round 6
// 294.734 us; speedup vs baseline: 8.6587x; 1.1140x over previous
//
#include <hip/hip_runtime.h>
#include <math.h>

#define CDIV(a,b) (((a)+(b)-1)/(b))

// ---------- deg[dst]++ (int histogram) ----------
__global__ __launch_bounds__(256) void deg_kernel(
    const int* __restrict__ dst, int E, int* __restrict__ deg)
{
    int e = blockIdx.x * 256 + threadIdx.x;
    if (e >= E) return;
    atomicAdd(&deg[dst[e]], 1);
}

__global__ __launch_bounds__(256) void dinv_kernel(
    const int* __restrict__ deg, float* __restrict__ dinv, int N)
{
    int i = blockIdx.x * 256 + threadIdx.x;
    if (i >= N) return;
    dinv[i] = 1.0f / sqrtf((float)deg[i] + 1.0f);  // +1 for self-loop
}

// ---------- hierarchical exclusive scan ----------
__global__ __launch_bounds__(1024) void block_scan_kernel(
    const int* __restrict__ deg, int* __restrict__ excl,
    int* __restrict__ bsums, int N)
{
    __shared__ int buf[1024];
    const int t = threadIdx.x;
    const int i = blockIdx.x * 1024 + t;
    int v = (i < N) ? deg[i] : 0;
    buf[t] = v;
    __syncthreads();
    for (int offs = 1; offs < 1024; offs <<= 1) {
        int add = (t >= offs) ? buf[t - offs] : 0;
        __syncthreads();
        buf[t] += add;
        __syncthreads();
    }
    if (i < N) excl[i] = buf[t] - v;
    if (t == 1023) bsums[blockIdx.x] = buf[t];
}

__global__ __launch_bounds__(1024) void scan_bsums_kernel(
    int* __restrict__ bsums, int nb)
{
    __shared__ int buf[1024];
    const int t = threadIdx.x;
    int v = (t < nb) ? bsums[t] : 0;
    buf[t] = v;
    __syncthreads();
    for (int offs = 1; offs < 1024; offs <<= 1) {
        int add = (t >= offs) ? buf[t - offs] : 0;
        __syncthreads();
        buf[t] += add;
        __syncthreads();
    }
    if (t < nb) bsums[t] = buf[t] - v;  // exclusive
}

__global__ __launch_bounds__(256) void add_offsets_kernel(
    int* __restrict__ rowptr, int* __restrict__ cursor,
    const int* __restrict__ bsums, int N, int E)
{
    int i = blockIdx.x * 256 + threadIdx.x;
    if (i < N) {
        int v = rowptr[i] + bsums[i >> 10];
        rowptr[i] = v;
        cursor[i] = v;
    }
    if (i == N) rowptr[N] = E;
}

// ---------- scatter edges into CSR slots ----------
__global__ __launch_bounds__(256) void csr_build_kernel(
    const int* __restrict__ src, const int* __restrict__ dst,
    int* __restrict__ cursor, int* __restrict__ csr_src, int E)
{
    int e = blockIdx.x * 256 + threadIdx.x;
    if (e >= E) return;
    int pos = atomicAdd(&cursor[dst[e]], 1);
    csr_src[pos] = src[e];
}

// ---------- GEMM: tmp = A@W ----------
// W (col-slice) staged in LDS ONCE, single barrier, then barrier-free k-loop.
// A read directly from global: the CT lanes of a row-group hit the same
// float4 address -> one broadcast transaction, L1/L2-served.
template<int FI, int FO, int COLS, int ROWS>
__global__ __launch_bounds__(256, 4) void gemm_kernel(
    const float* __restrict__ A, const float* __restrict__ W,
    float* __restrict__ tmp, int N)
{
    constexpr int NCB = FO / COLS;    // col-blocks
    constexpr int CT  = COLS / 4;     // col-threads (float4 each)
    constexpr int RT  = 256 / CT;     // row-threads
    constexpr int RPT = ROWS / RT;    // rows per thread

    __shared__ float sW[FI][COLS];

    const int t    = threadIdx.x;
    const int colb = (NCB > 1) ? (blockIdx.x % NCB) : 0;
    const int rowb = (NCB > 1) ? (blockIdx.x / NCB) : blockIdx.x;

    // stage W col-slice: FI x COLS
    #pragma unroll
    for (int it = 0; it < (FI * COLS / 4) / 256; ++it) {
        int idx = it * 256 + t;
        int k   = idx / CT;
        int cq  = idx % CT;
        *reinterpret_cast<float4*>(&sW[k][cq * 4]) =
            *reinterpret_cast<const float4*>(W + (size_t)k * FO + colb * COLS + cq * 4);
    }
    __syncthreads();

    const int c0 = (t % CT) * 4;
    const int r0 = t / CT;

    const float* aptr[RPT];
    #pragma unroll
    for (int rr = 0; rr < RPT; ++rr) {
        int row = rowb * ROWS + r0 + rr * RT;
        int rc  = (row < N) ? row : (N - 1);   // clamp loads, guard stores
        aptr[rr] = A + (size_t)rc * FI;
    }

    float acc[RPT][4];
    #pragma unroll
    for (int rr = 0; rr < RPT; ++rr)
        #pragma unroll
        for (int c = 0; c < 4; ++c) acc[rr][c] = 0.0f;

    #pragma unroll 8
    for (int k4 = 0; k4 < FI / 4; ++k4) {
        float4 w0 = *reinterpret_cast<const float4*>(&sW[k4 * 4 + 0][c0]);
        float4 w1 = *reinterpret_cast<const float4*>(&sW[k4 * 4 + 1][c0]);
        float4 w2 = *reinterpret_cast<const float4*>(&sW[k4 * 4 + 2][c0]);
        float4 w3 = *reinterpret_cast<const float4*>(&sW[k4 * 4 + 3][c0]);
        #pragma unroll
        for (int rr = 0; rr < RPT; ++rr) {
            float4 a = *reinterpret_cast<const float4*>(aptr[rr] + k4 * 4);
            acc[rr][0] += a.x * w0.x + a.y * w1.x + a.z * w2.x + a.w * w3.x;
            acc[rr][1] += a.x * w0.y + a.y * w1.y + a.z * w2.y + a.w * w3.y;
            acc[rr][2] += a.x * w0.z + a.y * w1.z + a.z * w2.z + a.w * w3.z;
            acc[rr][3] += a.x * w0.w + a.y * w1.w + a.z * w2.w + a.w * w3.w;
        }
    }

    #pragma unroll
    for (int rr = 0; rr < RPT; ++rr) {
        int row = rowb * ROWS + r0 + rr * RT;
        if (row >= N) continue;
        *reinterpret_cast<float4*>(tmp + (size_t)row * FO + colb * COLS + c0) =
            make_float4(acc[rr][0], acc[rr][1], acc[rr][2], acc[rr][3]);
    }
}

// ---------- gather-side aggregation + self-loop + bias + ReLU (+ fused final) ----------
template<int FO, bool RELU, bool FINAL>
__global__ __launch_bounds__(256) void agg_kernel(
    const int* __restrict__ rowptr, const int* __restrict__ csr_src,
    const float* __restrict__ dinv, const float* __restrict__ tmp,
    const float* __restrict__ b, float* __restrict__ h,
    const float* __restrict__ Wl, const float* __restrict__ bl,
    float* __restrict__ out, int N)
{
    constexpr int GPW = (FO == 32) ? 2 : 1;   // node-groups per wave
    constexpr int GL  = 64 / GPW;             // lanes per group
    constexpr int FPL = FO / GL;              // floats per lane (2 for FO=128, else 1)
    const int wid  = (blockIdx.x * 256 + threadIdx.x) >> 6;
    const int lane = threadIdx.x & 63;
    const int g    = lane / GL;
    const int fl   = lane % GL;
    const int node = wid * GPW + g;
    if (node >= N) return;

    float acc0[FPL], acc1[FPL], acc2[FPL], acc3[FPL];
    #pragma unroll
    for (int q = 0; q < FPL; ++q) { acc0[q] = 0.f; acc1[q] = 0.f; acc2[q] = 0.f; acc3[q] = 0.f; }

    const float dvd = dinv[node];
    const int jb = rowptr[node], je = rowptr[node + 1];
    int j = jb;
    for (; j + 4 <= je; j += 4) {
        int s0 = csr_src[j + 0];
        int s1 = csr_src[j + 1];
        int s2 = csr_src[j + 2];
        int s3 = csr_src[j + 3];
        float w0 = dinv[s0] * dvd;
        float w1 = dinv[s1] * dvd;
        float w2 = dinv[s2] * dvd;
        float w3 = dinv[s3] * dvd;
        if (FPL == 2) {
            float2 v0 = *reinterpret_cast<const float2*>(tmp + (size_t)s0 * FO + fl * 2);
            float2 v1 = *reinterpret_cast<const float2*>(tmp + (size_t)s1 * FO + fl * 2);
            float2 v2 = *reinterpret_cast<const float2*>(tmp + (size_t)s2 * FO + fl * 2);
            float2 v3 = *reinterpret_cast<const float2*>(tmp + (size_t)s3 * FO + fl * 2);
            acc0[0] += v0.x * w0; acc0[FPL - 1] += v0.y * w0;
            acc1[0] += v1.x * w1; acc1[FPL - 1] += v1.y * w1;
            acc2[0] += v2.x * w2; acc2[FPL - 1] += v2.y * w2;
            acc3[0] += v3.x * w3; acc3[FPL - 1] += v3.y * w3;
        } else {
            acc0[0] += tmp[(size_t)s0 * FO + fl] * w0;
            acc1[0] += tmp[(size_t)s1 * FO + fl] * w1;
            acc2[0] += tmp[(size_t)s2 * FO + fl] * w2;
            acc3[0] += tmp[(size_t)s3 * FO + fl] * w3;
        }
    }
    for (; j < je; ++j) {
        int s = csr_src[j];
        float w = dinv[s] * dvd;
        const float* p = tmp + (size_t)s * FO + fl * FPL;
        #pragma unroll
        for (int q = 0; q < FPL; ++q) acc0[q] += p[q] * w;
    }
    // self-loop
    const float* ps = tmp + (size_t)node * FO + fl * FPL;
    const float d2 = dvd * dvd;
    #pragma unroll
    for (int q = 0; q < FPL; ++q) acc1[q] += ps[q] * d2;

    if (FINAL) {
        // v = relu(agg + b); r = v * Wl; 32-lane reduce; out[node] = r + bl
        float v = ((acc0[0] + acc1[0]) + (acc2[0] + acc3[0])) + b[fl];
        v = fmaxf(v, 0.0f);
        float r = v * Wl[fl];
        #pragma unroll
        for (int offd = 16; offd > 0; offd >>= 1)
            r += __shfl_down(r, offd, 32);
        if (fl == 0) out[node] = r + bl[0];
    } else {
        float* o = h + (size_t)node * FO + fl * FPL;
        #pragma unroll
        for (int q = 0; q < FPL; ++q) {
            float v = ((acc0[q] + acc1[q]) + (acc2[q] + acc3[q])) + b[fl * FPL + q];
            o[q] = RELU ? fmaxf(v, 0.0f) : v;
        }
    }
}

extern "C" void kernel_launch(void* const* d_in, const int* in_sizes, int n_in,
                              void* d_out, int out_size, void* d_ws, size_t ws_size,
                              hipStream_t stream)
{
    const float* x  = (const float*)d_in[0];
    const int*   ei = (const int*)d_in[1];   // int inputs arrive as int32
    const float* W1 = (const float*)d_in[2];
    const float* b1 = (const float*)d_in[3];
    const float* W2 = (const float*)d_in[4];
    const float* b2 = (const float*)d_in[5];
    const float* W3 = (const float*)d_in[6];
    const float* b3 = (const float*)d_in[7];
    const float* Wl = (const float*)d_in[8];
    const float* bl = (const float*)d_in[9];
    float* out = (float*)d_out;

    const int N = in_sizes[0] / 128;
    const int E = in_sizes[1] / 2;

    const int* src = ei;        // edge_index row 0
    const int* dst = ei + E;    // edge_index row 1

    char* ws = (char*)d_ws;
    size_t off = 0;
    auto wsalloc = [&](size_t bytes) -> void* {
        void* p = ws + off;
        off = (off + bytes + 255) & ~(size_t)255;
        return p;
    };
    const int NB = CDIV(N, 1024);
    int*   deg     = (int*)  wsalloc((size_t)N * 4);
    float* dinv    = (float*)wsalloc((size_t)N * 4);
    int*   rowptr  = (int*)  wsalloc((size_t)(N + 1) * 4);
    int*   cursor  = (int*)  wsalloc((size_t)N * 4);
    int*   bsums   = (int*)  wsalloc((size_t)NB * 4);
    int*   csr_src = (int*)  wsalloc((size_t)E * 4);
    float* B1      = (float*)wsalloc((size_t)N * 128 * 4);  // tmp
    float* B2      = (float*)wsalloc((size_t)N * 128 * 4);  // h
    // total ws use: ~55 MB

    // ---- CSR build ----
    hipMemsetAsync(deg, 0, (size_t)N * 4, stream);
    deg_kernel<<<CDIV(E, 256), 256, 0, stream>>>(dst, E, deg);
    dinv_kernel<<<CDIV(N, 256), 256, 0, stream>>>(deg, dinv, N);
    block_scan_kernel<<<NB, 1024, 0, stream>>>(deg, rowptr, bsums, N);
    scan_bsums_kernel<<<1, 1024, 0, stream>>>(bsums, NB);
    add_offsets_kernel<<<CDIV(N + 1, 256), 256, 0, stream>>>(rowptr, cursor, bsums, N, E);
    csr_build_kernel<<<CDIV(E, 256), 256, 0, stream>>>(src, dst, cursor, csr_src, E);

    // ---- layer 1: 128 -> 128 (col-split x2) ----
    gemm_kernel<128, 128, 64, 64><<<2 * CDIV(N, 64), 256, 0, stream>>>(x, W1, B1, N);
    agg_kernel<128, true, false><<<CDIV(N, 4), 256, 0, stream>>>(
        rowptr, csr_src, dinv, B1, b1, B2, nullptr, nullptr, nullptr, N);

    // ---- layer 2: 128 -> 64 ----
    gemm_kernel<128, 64, 64, 64><<<CDIV(N, 64), 256, 0, stream>>>(B2, W2, B1, N);
    agg_kernel<64, true, false><<<CDIV(N, 4), 256, 0, stream>>>(
        rowptr, csr_src, dinv, B1, b2, B2, nullptr, nullptr, nullptr, N);

    // ---- layer 3: 64 -> 32, final linear fused into agg ----
    gemm_kernel<64, 32, 32, 64><<<CDIV(N, 64), 256, 0, stream>>>(B2, W3, B1, N);
    agg_kernel<32, true, true><<<CDIV(N, 8), 256, 0, stream>>>(
        rowptr, csr_src, dinv, B1, b3, nullptr, Wl, bl, out, N);
}